// Round 14
// baseline (330.461 us; speedup 1.0000x reference)
//
#include <hip/hip_runtime.h>
#include <hip/hip_bf16.h>

#define T_TOK 16384
#define D_DIM 2048
#define E_EXP 64
#define TAU   2e-3f

// workspace layout (bytes)
#define WS_WP   0                    // float4[512][64] = 512KB packed W^T
#define WS_SUM  (512*1024)           // double[64] expert prob sums
#define WS_CNT  (512*1024 + 512)     // int flag count
#define WS_FLG  (512*1024 + 1024)    // int[T] flagged rows

__device__ __forceinline__ void ins3(float& v1, int& i1, float& v2, int& i2,
                                     float& v3, int& i3, float v, int i){
  if (v > v1 || (v == v1 && i < i1)) { v3=v2; i3=i2; v2=v1; i2=i1; v1=v; i1=i; }
  else if (v > v2 || (v == v2 && i < i2)) { v3=v2; i3=i2; v2=v; i2=i; }
  else if (v > v3 || (v == v3 && i < i3)) { v3=v; i3=i; }
}

// Pack W[64][2048] -> WP[kk][e] (kk = k/4, float4 of 4 consecutive k).
// Reads coalesced along kk; scattered 16B writes (small kernel, L2 absorbs).
__global__ void wpack_kernel(const float* __restrict__ W, float4* __restrict__ WP,
                             double* __restrict__ ESUM, int* __restrict__ FCNT){
  const int n = blockIdx.x * 256 + threadIdx.x;   // 128 blocks -> 32768 = 64e x 512kk
  if (blockIdx.x == 0){
    if (threadIdx.x < 64) ESUM[threadIdx.x] = 0.0;
    else if (threadIdx.x == 64) *FCNT = 0;
  }
  const int e  = n >> 9;          // coalesced read side
  const int kk = n & 511;
  float4 v = *reinterpret_cast<const float4*>(W + (size_t)e*D_DIM + kk*4);
  WP[(size_t)kk*64 + e] = v;
}

// Main fused kernel — pure-VALU fp32 formulation (lane = expert).
// Grid 512 x 512thr (2 blocks/CU, 16 waves/CU). Block = 32 rows.
// Wave = (kh = k-half, rg = row-group): 8 rows x 1024 k, acc[8] per lane.
// W: WP[kk][lane] lane-coalesced float4 loads (L2-resident, 512KB).
// X: wave-uniform float4 loads (all lanes same address -> 1 line/request).
// No LDS / barriers in the main loop; no MFMA; no hi/lo split (fp32 error
// ~3e-6 << TAU=2e-3, fp64 fixup still guarantees exact ids).
__launch_bounds__(512, 4)
__global__ void moe_main(const float* __restrict__ X, const float* __restrict__ NZ,
                         const float4* __restrict__ WP, const float* __restrict__ NW,
                         float* __restrict__ OUT, double* __restrict__ ESUM,
                         int* __restrict__ FCNT, int* __restrict__ FLIST)
{
  __shared__ float lgts[32*64];    // 8KB
  __shared__ float nzs [32*64];    // 8KB
  __shared__ float prb [32*64];    // 8KB
  __shared__ float nws [64];

  const int tid  = threadIdx.x;
  const int lane = tid & 63;       // = expert
  const int wv   = tid >> 6;       // 0..7
  const int kh   = wv & 1;         // k half (1024)
  const int rg   = wv >> 1;        // row group (8 rows)
  const int r0   = (blockIdx.x << 5) + rg*8;

  const float4* wp = WP + (size_t)(kh*256)*64 + lane;   // lane-coalesced
  const float*  xb = X + (size_t)r0*D_DIM + kh*1024;    // wave-uniform

  float acc[8];
  #pragma unroll
  for (int r = 0; r < 8; ++r) acc[r] = 0.0f;

  #pragma unroll 2
  for (int kb = 0; kb < 128; ++kb){              // 8 k per iter
    float4 w0 = wp[(size_t)(kb*2    )*64];
    float4 w1 = wp[(size_t)(kb*2 + 1)*64];
    #pragma unroll
    for (int r = 0; r < 8; ++r){
      const float* xp = xb + (size_t)r*D_DIM + kb*8;
      float4 xa = *reinterpret_cast<const float4*>(xp);
      float4 xc = *reinterpret_cast<const float4*>(xp + 4);
      float s = acc[r];
      s = fmaf(xa.x, w0.x, s); s = fmaf(xa.y, w0.y, s);
      s = fmaf(xa.z, w0.z, s); s = fmaf(xa.w, w0.w, s);
      s = fmaf(xc.x, w1.x, s); s = fmaf(xc.y, w1.y, s);
      s = fmaf(xc.z, w1.z, s); s = fmaf(xc.w, w1.w, s);
      acc[r] = s;
    }
  }

  // ---- K-half reduction (deterministic 2-phase) ----
  if (kh == 0){
    #pragma unroll
    for (int r = 0; r < 8; ++r) lgts[(rg*8 + r)*64 + lane] = acc[r];
  }
  __syncthreads();
  if (kh == 1){
    #pragma unroll
    for (int r = 0; r < 8; ++r) lgts[(rg*8 + r)*64 + lane] += acc[r];
  }

  // stage noise + noise_weight (32 rows x 64)
  const int sr = tid >> 4, sc = tid & 15;
  *reinterpret_cast<float4*>(&nzs[sr*64 + sc*4]) =
    *reinterpret_cast<const float4*>(NZ + (size_t)((blockIdx.x << 5) + sr)*E_EXP + sc*4);
  if (tid < 64) nws[tid] = NW[tid];
  __syncthreads();

  // gating: waves 0..3, 8 lanes per row, 8 experts per lane (32 rows)
  if (wv < 4){
    const int rrow = (wv << 3) + (lane >> 3);
    const int j    = lane & 7;
    const int trow = (blockIdx.x << 5) + rrow;
    float cl[8];
    float v1 = -INFINITY, v2 = -INFINITY, v3 = -INFINITY;
    int   i1 = 1 << 29,   i2 = 1 << 29,   i3 = 1 << 29;
    #pragma unroll
    for (int mm = 0; mm < 8; ++mm){
      int q = j + (mm << 3);
      float lg = lgts[rrow*64 + q];
      cl[mm] = lg;
      float vn = fmaf(nzs[rrow*64 + q], nws[q], lg);   // NOISY_STD = 1
      ins3(v1,i1,v2,i2,v3,i3, vn, q);
    }
    #pragma unroll
    for (int d = 1; d < 8; d <<= 1){
      float ov1 = __shfl_xor(v1, d, 8), ov2 = __shfl_xor(v2, d, 8), ov3 = __shfl_xor(v3, d, 8);
      int   oi1 = __shfl_xor(i1, d, 8), oi2 = __shfl_xor(i2, d, 8), oi3 = __shfl_xor(i3, d, 8);
      ins3(v1,i1,v2,i2,v3,i3, ov1, oi1);
      ins3(v1,i1,v2,i2,v3,i3, ov2, oi2);
      ins3(v1,i1,v2,i2,v3,i3, ov3, oi3);
    }
    float e1 = expf(v2 - v1);
    float g0g = 1.0f / (1.0f + e1);
    float g1g = e1 * g0g;

    float mx = cl[0];
    #pragma unroll
    for (int mm = 1; mm < 8; ++mm) mx = fmaxf(mx, cl[mm]);
    #pragma unroll
    for (int d = 1; d < 8; d <<= 1) mx = fmaxf(mx, __shfl_xor(mx, d, 8));
    float sum = 0.0f, exv[8];
    #pragma unroll
    for (int mm = 0; mm < 8; ++mm){ exv[mm] = expf(cl[mm] - mx); sum += exv[mm]; }
    #pragma unroll
    for (int d = 1; d < 8; d <<= 1) sum += __shfl_xor(sum, d, 8);
    float inv = 1.0f / sum;
    #pragma unroll
    for (int mm = 0; mm < 8; ++mm) prb[rrow*64 + j + (mm << 3)] = exv[mm] * inv;

    if (j == 0){
      OUT[(size_t)T_TOK*E_EXP + (size_t)trow*2]     = (float)i1;
      OUT[(size_t)T_TOK*E_EXP + (size_t)trow*2 + 1] = (float)i2;
      if ((v1 - v2 < TAU) || (v2 - v3 < TAU)){   // near-tie -> fp64 fixup
        int slot = atomicAdd(FCNT, 1);
        FLIST[slot] = trow;
      }
    }
    #pragma unroll
    for (int mm = 0; mm < 8; ++mm){
      int q = j + (mm << 3);
      lgts[rrow*64 + q] = (q == i1) ? g0g : ((q == i2) ? g1g : 0.0f);
    }
  }
  __syncthreads();

  // coalesced gates write (512 threads x float4)
  *reinterpret_cast<float4*>(OUT + (size_t)((blockIdx.x << 5) + sr)*E_EXP + sc*4) =
    *reinterpret_cast<const float4*>(&lgts[sr*64 + sc*4]);
  // per-expert prob column sums -> one f64 atomic per expert per block
  if (tid < 64){
    float s0 = 0.0f;
    #pragma unroll 8
    for (int rr2 = 0; rr2 < 32; ++rr2) s0 += prb[rr2*64 + tid];
    atomicAdd(&ESUM[tid], (double)s0);
  }
}

// Merged finalize: block 0 = load-balance loss (parallel ESUM reads);
// blocks 1..511 grid-stride the COMPACT near-tie list (fp64 recompute).
__launch_bounds__(256)
__global__ void moe_finalize(const float* __restrict__ X, const float* __restrict__ NZ,
                             const float* __restrict__ WG, const float* __restrict__ NW,
                             float* __restrict__ OUT, const double* __restrict__ ESUM,
                             const int* __restrict__ FCNT, const int* __restrict__ FLIST)
{
  if (blockIdx.x == 0){
    if (threadIdx.x < 64){
      const int e = threadIdx.x;
      double d = ESUM[e] * (1.0 / T_TOK) - (1.0 / 64.0);
      double sq = d * d;
      #pragma unroll
      for (int off = 1; off < 64; off <<= 1) sq += __shfl_xor(sq, off, 64);
      if (e == 0) OUT[(size_t)T_TOK*E_EXP + T_TOK*2] = (float)(sq * (0.01 / 64.0));
    }
    return;
  }

  __shared__ __align__(16) float xl[2048];
  __shared__ double lz[64];
  __shared__ int   si1, si2;
  __shared__ float sg0, sg1;
  const int n    = *FCNT;
  const int lane = threadIdx.x & 63;
  const int wv   = threadIdx.x >> 6;
  for (int idx = blockIdx.x - 1; idx < n; idx += 511){
    const int t = FLIST[idx];
    {
      int off = threadIdx.x * 8;
      *reinterpret_cast<float4*>(xl + off) =
        *reinterpret_cast<const float4*>(X + (size_t)t*D_DIM + off);
      *reinterpret_cast<float4*>(xl + off + 4) =
        *reinterpret_cast<const float4*>(X + (size_t)t*D_DIM + off + 4);
    }
    __syncthreads();
    for (int s = 0; s < 16; ++s){
      const int e = wv*16 + s;
      const float* wr = WG + (size_t)e*D_DIM;
      double acc = 0.0;
      #pragma unroll
      for (int it = 0; it < 8; ++it){
        float4 w4 = *reinterpret_cast<const float4*>(wr + it*256 + lane*4);
        float4 x4 = *reinterpret_cast<const float4*>(xl + it*256 + lane*4);
        acc += (double)x4.x * (double)w4.x;
        acc += (double)x4.y * (double)w4.y;
        acc += (double)x4.z * (double)w4.z;
        acc += (double)x4.w * (double)w4.w;
      }
      #pragma unroll
      for (int off = 1; off < 64; off <<= 1) acc += __shfl_xor(acc, off, 64);
      if (lane == 0)
        lz[e] = acc + (double)NZ[(size_t)t*E_EXP + e] * (double)NW[e];
    }
    __syncthreads();
    if (threadIdx.x == 0){
      double b1 = -1e300, b2 = -1e300; int j1 = 0, j2 = 0;
      for (int q = 0; q < 64; ++q){
        double v = lz[q];
        if (v > b1){ b2 = b1; j2 = j1; b1 = v; j1 = q; }
        else if (v > b2){ b2 = v; j2 = q; }
      }
      double ee = exp(b2 - b1);
      sg0 = (float)(1.0 / (1.0 + ee));
      sg1 = (float)(ee / (1.0 + ee));
      si1 = j1; si2 = j2;
      OUT[(size_t)T_TOK*E_EXP + (size_t)t*2]     = (float)j1;
      OUT[(size_t)T_TOK*E_EXP + (size_t)t*2 + 1] = (float)j2;
    }
    __syncthreads();
    if (threadIdx.x < 64)
      OUT[(size_t)t*E_EXP + threadIdx.x] = (threadIdx.x == si1) ? sg0 :
                                           ((threadIdx.x == si2) ? sg1 : 0.0f);
    __syncthreads();
  }
}

extern "C" void kernel_launch(void* const* d_in, const int* in_sizes, int n_in,
                              void* d_out, int out_size, void* d_ws, size_t ws_size,
                              hipStream_t stream)
{
  const float* X  = (const float*)d_in[0];
  const float* NZ = (const float*)d_in[1];
  const float* WG = (const float*)d_in[2];
  const float* NW = (const float*)d_in[3];
  float* OUT = (float*)d_out;
  char*  ws  = (char*)d_ws;
  float4* WP = (float4*)(ws + WS_WP);
  double* ESUM = (double*)(ws + WS_SUM);
  int* FCNT  = (int*)(ws + WS_CNT);
  int* FLIST = (int*)(ws + WS_FLG);

  wpack_kernel<<<dim3(128), dim3(256), 0, stream>>>(WG, WP, ESUM, FCNT);
  moe_main<<<dim3(T_TOK/32), dim3(512), 0, stream>>>(X, NZ, WP, NW, OUT, ESUM, FCNT, FLIST);
  moe_finalize<<<dim3(512), dim3(256), 0, stream>>>(X, NZ, WG, NW, OUT, ESUM, FCNT, FLIST);
}

// Round 15
// 154.246 us; speedup vs baseline: 2.1424x; 2.1424x over previous
//
#include <hip/hip_runtime.h>
#include <hip/hip_bf16.h>

#define T_TOK 16384
#define D_DIM 2048
#define E_EXP 64
#define TAU   2e-3f

typedef __bf16 bf16x8 __attribute__((ext_vector_type(8)));
typedef float  f32x16 __attribute__((ext_vector_type(16)));
typedef unsigned short ushort_t;

// workspace layout (bytes)
#define WS_WHI  0                    // ushort[16 chunks][1024 granule-slots][8] = 256KB
#define WS_WLO  (256*1024)
#define WS_SUM  (512*1024)           // double[64] expert prob sums
#define WS_DONE (512*1024 + 512)     // int completion ticket

__device__ __forceinline__ unsigned short bf16_rne(float x){
  unsigned int u = __float_as_uint(x);
  return (unsigned short)((u + 0x7FFFu + ((u >> 16) & 1u)) >> 16);
}

__device__ __forceinline__ void ins3(float& v1, int& i1, float& v2, int& i2,
                                     float& v3, int& i3, float v, int i){
  if (v > v1 || (v == v1 && i < i1)) { v3=v2; i3=i2; v2=v1; i2=i1; v1=v; i1=i; }
  else if (v > v2 || (v == v2 && i < i2)) { v3=v2; i3=i2; v2=v; i2=i; }
  else if (v > v3 || (v == v3 && i < i3)) { v3=v; i3=i; }
}

__device__ __forceinline__ void gload16(const void* g, const void* l){
  __builtin_amdgcn_global_load_lds(
      (const __attribute__((address_space(1))) unsigned int*)g,
      (__attribute__((address_space(3))) unsigned int*)l, 16, 0, 0);
}

// Fragment-pack W hi/lo bf16 (same layout R10's main reads) — COALESCED reads:
// block b handles W row e=b (contiguous 8KB); scattered 16B writes -> L2.
// Granule G = c*1024 + w*128 + eh*64 + kg*32 + m holds
// W[eh*32+m][c*128 + w*16 + kg*8 + j]  (eh=e>>5, m=e&31).
__global__ void wsplit_kernel(const float* __restrict__ W,
                              ushort_t* __restrict__ whi, ushort_t* __restrict__ wlo,
                              double* __restrict__ ESUM, int* __restrict__ DONE){
  const int t = threadIdx.x;               // 64 blocks x 256 thr
  const int e = blockIdx.x;
  if (e == 0){
    if (t < 64) ESUM[t] = 0.0;
    else if (t == 64) *DONE = 0;
  }
  const int k0 = t * 8;
  const float* src = W + (size_t)e*D_DIM + k0;
  float4 w0 = *reinterpret_cast<const float4*>(src);
  float4 w1 = *reinterpret_cast<const float4*>(src + 4);
  float f[8] = {w0.x,w0.y,w0.z,w0.w,w1.x,w1.y,w1.z,w1.w};
  unsigned h[8], lo[8];
  #pragma unroll
  for (int i = 0; i < 8; ++i){
    h[i]  = bf16_rne(f[i]);
    lo[i] = bf16_rne(f[i] - __uint_as_float(h[i] << 16));
  }
  uint4 hv = { h[0]|(h[1]<<16),  h[2]|(h[3]<<16),  h[4]|(h[5]<<16),  h[6]|(h[7]<<16) };
  uint4 lv = { lo[0]|(lo[1]<<16), lo[2]|(lo[3]<<16), lo[4]|(lo[5]<<16), lo[6]|(lo[7]<<16) };
  const int eh = e >> 5, m = e & 31;
  const int c  = k0 >> 7;
  const int w  = (k0 >> 4) & 7;
  const int kg = (k0 >> 3) & 1;
  const int G  = c*1024 + w*128 + eh*64 + kg*32 + m;
  *reinterpret_cast<uint4*>(whi + (size_t)G*8) = hv;
  *reinterpret_cast<uint4*>(wlo + (size_t)G*8) = lv;
}

// Fully-fused main: R10 mainloop VERBATIM (74.4us empirical best) + gating +
// IN-BLOCK fp64 near-tie fixup (LDS flags, no FLIST) + last-block loss
// (threadfence + DONE ticket; ESUM read via atomic RMW for XCD coherence).
__launch_bounds__(512, 4)
__global__ void moe_main(const float* __restrict__ X, const float* __restrict__ NZ,
                         const ushort_t* __restrict__ WHI, const ushort_t* __restrict__ WLO,
                         const float* __restrict__ NW, const float* __restrict__ WG,
                         float* __restrict__ OUT, double* __restrict__ ESUM,
                         int* __restrict__ DONE)
{
  __shared__ __align__(16) char smem[32768];

  const int tid  = threadIdx.x;
  const int lane = tid & 63;
  const int wv   = tid >> 6;   // 0..7
  const int eh   = wv & 1;     // expert half
  const int ks   = wv >> 1;    // K quarter of each chunk
  const int r0   = blockIdx.x << 5;
  const int m    = lane & 31;
  const int kg   = lane >> 5;

  // --- X staging addresses (per-lane source, wave-uniform LDS dst) ---
  const int n0   = wv*64 + lane;
  const int row0 = n0 >> 5, g0 = n0 & 31;
  const int gs0  = (g0 & 24) | ((g0 ^ row0) & 7);
  const char* px0 = (const char*)X + ((size_t)(r0 + row0)*D_DIM + gs0*4) * 4;
  const char* px1 = px0 + (size_t)16*D_DIM*4;
  const char* ldsx0 = smem +        wv*1024;
  const char* ldsx1 = smem + 8192 + wv*1024;

  const char* pwh = (const char*)WHI + (size_t)(ks*256 + eh*64 + lane)*16;
  const char* pwl = (const char*)WLO + (size_t)(ks*256 + eh*64 + lane)*16;

  const int gf0 = ks*8 + kg*2;
  const int gf1 = gf0 + 4;
  const int offA0 = m*512 + (((gf0  ) & 24) | (((gf0  ) ^ m) & 7))*16;
  const int offB0 = m*512 + (((gf0+1) & 24) | (((gf0+1) ^ m) & 7))*16;
  const int offA1 = m*512 + (((gf1  ) & 24) | (((gf1  ) ^ m) & 7))*16;
  const int offB1 = m*512 + (((gf1+1) & 24) | (((gf1+1) ^ m) & 7))*16;

  f32x16 acc;
  #pragma unroll
  for (int i = 0; i < 16; ++i) acc[i] = 0.0f;

  uint4 whA0, wlA0, whA1, wlA1;
  uint4 whB0, wlB0, whB1, wlB1;

  #define LOADW(c, H0, L0, H1, L1) do{                                         \
    H0 = *reinterpret_cast<const uint4*>(pwh + (size_t)(c)*16384);             \
    L0 = *reinterpret_cast<const uint4*>(pwl + (size_t)(c)*16384);             \
    H1 = *reinterpret_cast<const uint4*>(pwh + (size_t)(c)*16384 + 2048);      \
    L1 = *reinterpret_cast<const uint4*>(pwl + (size_t)(c)*16384 + 2048);      \
  }while(0)

  #define ISSUE(c, BUF, H0, L0, H1, L1) do{                                    \
    __builtin_amdgcn_sched_barrier(0);                                         \
    gload16(px0 + (size_t)(c)*512, ldsx0 + (BUF));                             \
    gload16(px1 + (size_t)(c)*512, ldsx1 + (BUF));                             \
    LOADW(c, H0, L0, H1, L1);                                                  \
    __builtin_amdgcn_sched_barrier(0);                                         \
  }while(0)

  #define CVT8(fa, fb, ah, al) do{                                             \
    float fv[8] = {fa.x,fa.y,fa.z,fa.w,fb.x,fb.y,fb.z,fb.w};                   \
    _Pragma("unroll")                                                          \
    for (int ii = 0; ii < 8; ++ii){                                            \
      __bf16 hh = (__bf16)fv[ii];                                              \
      ah[ii] = hh; al[ii] = (__bf16)(fv[ii] - (float)hh);                      \
    }                                                                          \
  }while(0)

  #define KS2(BUF, OA, OB, WH, WL) do{                                         \
    float4 fa = *reinterpret_cast<const float4*>(smem + (BUF) + (OA));         \
    float4 fb = *reinterpret_cast<const float4*>(smem + (BUF) + (OB));         \
    bf16x8 ah, al;                                                             \
    CVT8(fa, fb, ah, al);                                                      \
    bf16x8 bh = __builtin_bit_cast(bf16x8, WH);                                \
    bf16x8 bl = __builtin_bit_cast(bf16x8, WL);                                \
    acc = __builtin_amdgcn_mfma_f32_32x32x16_bf16(ah, bh, acc, 0, 0, 0);       \
    acc = __builtin_amdgcn_mfma_f32_32x32x16_bf16(ah, bl, acc, 0, 0, 0);       \
    acc = __builtin_amdgcn_mfma_f32_32x32x16_bf16(al, bh, acc, 0, 0, 0);       \
  }while(0)

  #define PHASE(cc, H0, L0, H1, L1, BUF, WNTOK, DOISS) do{                     \
    asm volatile("s_waitcnt vmcnt(" WNTOK ")" ::: "memory");                   \
    __builtin_amdgcn_sched_barrier(0);                                         \
    __builtin_amdgcn_s_barrier();                                              \
    KS2(BUF, offA0, offB0, H0, L0);                                            \
    KS2(BUF, offA1, offB1, H1, L1);                                            \
    __builtin_amdgcn_s_barrier();                                              \
    if (DOISS) ISSUE((cc) + 2, BUF, H0, L0, H1, L1);                           \
  }while(0)

  ISSUE(0, 0,     whA0, wlA0, whA1, wlA1);
  ISSUE(1, 16384, whB0, wlB0, whB1, wlB1);

  #pragma unroll 1
  for (int g = 0; g < 7; ++g){
    PHASE(2*g,     whA0, wlA0, whA1, wlA1, 0,     "6", 1);
    PHASE(2*g + 1, whB0, wlB0, whB1, wlB1, 16384, "6", 1);
  }
  PHASE(14, whA0, wlA0, whA1, wlA1, 0,     "6", 0);
  PHASE(15, whB0, wlB0, whB1, wlB1, 16384, "0", 0);

  #undef PHASE
  #undef KS2
  #undef CVT8
  #undef ISSUE
  #undef LOADW

  // ---- epilogue: K-quarter reduction (deterministic 4-phase chain) ----
  float* lgts = (float*)(smem);            // [32][64] 0..8192
  float* nzs  = (float*)(smem + 8192);     // [32][64]
  float* prb  = (float*)(smem + 16384);    // [32][64]
  float* nws  = (float*)(smem + 24576);    // [64]   ..24832
  int*   flg  = (int*)(smem + 24832);      // [32]   ..24960
  double* lz  = (double*)(smem + 25088);   // [64]   ..25600
  int*   sfi  = (int*)(smem + 25600);      // [2]
  float* sfg  = (float*)(smem + 25616);    // [2]
  int*   stk  = (int*)(smem + 25632);      // [1] ticket
  const int ex = eh*32 + m;

  __syncthreads();
  if (ks == 0){
    #pragma unroll
    for (int r = 0; r < 16; ++r){
      int rr = (r & 3) + ((r >> 2) << 3) + (kg << 2);   // verified 32x32 C/D layout
      lgts[rr*64 + ex] = acc[r];
    }
  }
  __syncthreads();
  #pragma unroll
  for (int p = 1; p < 4; ++p){
    if (ks == p){
      #pragma unroll
      for (int r = 0; r < 16; ++r){
        int rr = (r & 3) + ((r >> 2) << 3) + (kg << 2);
        lgts[rr*64 + ex] += acc[r];
      }
    }
    __syncthreads();
  }

  // stage noise + noise_weight
  const int sr = tid >> 4, sc = tid & 15;
  *reinterpret_cast<float4*>(&nzs[sr*64 + sc*4]) =
    *reinterpret_cast<const float4*>(NZ + (size_t)(r0 + sr)*E_EXP + sc*4);
  if (tid < 64) nws[tid] = NW[tid];
  __syncthreads();

  // gating: waves 0..3, 8 lanes per row, 8 experts per lane
  if (wv < 4){
    const int rrow = (wv << 3) + (lane >> 3);
    const int j    = lane & 7;
    const int trow = r0 + rrow;
    float cl[8];
    float v1 = -INFINITY, v2 = -INFINITY, v3 = -INFINITY;
    int   i1 = 1 << 29,   i2 = 1 << 29,   i3 = 1 << 29;
    #pragma unroll
    for (int mm = 0; mm < 8; ++mm){
      int q = j + (mm << 3);
      float lg = lgts[rrow*64 + q];
      cl[mm] = lg;
      float vn = fmaf(nzs[rrow*64 + q], nws[q], lg);   // NOISY_STD = 1
      ins3(v1,i1,v2,i2,v3,i3, vn, q);
    }
    #pragma unroll
    for (int d = 1; d < 8; d <<= 1){
      float ov1 = __shfl_xor(v1, d, 8), ov2 = __shfl_xor(v2, d, 8), ov3 = __shfl_xor(v3, d, 8);
      int   oi1 = __shfl_xor(i1, d, 8), oi2 = __shfl_xor(i2, d, 8), oi3 = __shfl_xor(i3, d, 8);
      ins3(v1,i1,v2,i2,v3,i3, ov1, oi1);
      ins3(v1,i1,v2,i2,v3,i3, ov2, oi2);
      ins3(v1,i1,v2,i2,v3,i3, ov3, oi3);
    }
    float e1 = expf(v2 - v1);
    float g0g = 1.0f / (1.0f + e1);
    float g1g = e1 * g0g;

    float mx = cl[0];
    #pragma unroll
    for (int mm = 1; mm < 8; ++mm) mx = fmaxf(mx, cl[mm]);
    #pragma unroll
    for (int d = 1; d < 8; d <<= 1) mx = fmaxf(mx, __shfl_xor(mx, d, 8));
    float sum = 0.0f, exv[8];
    #pragma unroll
    for (int mm = 0; mm < 8; ++mm){ exv[mm] = expf(cl[mm] - mx); sum += exv[mm]; }
    #pragma unroll
    for (int d = 1; d < 8; d <<= 1) sum += __shfl_xor(sum, d, 8);
    float inv = 1.0f / sum;
    #pragma unroll
    for (int mm = 0; mm < 8; ++mm) prb[rrow*64 + j + (mm << 3)] = exv[mm] * inv;

    if (j == 0){
      OUT[(size_t)T_TOK*E_EXP + (size_t)trow*2]     = (float)i1;
      OUT[(size_t)T_TOK*E_EXP + (size_t)trow*2 + 1] = (float)i2;
      flg[rrow] = ((v1 - v2 < TAU) || (v2 - v3 < TAU)) ? 1 : 0;
    }
    #pragma unroll
    for (int mm = 0; mm < 8; ++mm){
      int q = j + (mm << 3);
      lgts[rrow*64 + q] = (q == i1) ? g0g : ((q == i2) ? g1g : 0.0f);
    }
  }
  __syncthreads();

  // coalesced gates write (512 threads x float4)
  *reinterpret_cast<float4*>(OUT + (size_t)(r0 + sr)*E_EXP + sc*4) =
    *reinterpret_cast<const float4*>(&lgts[sr*64 + sc*4]);
  // per-expert prob column sums -> one f64 atomic per expert per block
  if (tid < 64){
    float s0 = 0.0f;
    #pragma unroll 8
    for (int rr2 = 0; rr2 < 32; ++rr2) s0 += prb[rr2*64 + tid];
    atomicAdd(&ESUM[tid], (double)s0);
  }
  __syncthreads();

  // ---- in-block fp64 fixup of near-tie rows (rare; W fp32 from L2/L3) ----
  float* xl = (float*)(smem + 16384);      // reuse prb region (8KB)
  for (int rloc = 0; rloc < 32; ++rloc){
    if (flg[rloc] == 0) continue;          // uniform across block
    const int t = r0 + rloc;
    {
      int off = tid * 4;
      *reinterpret_cast<float4*>(xl + off) =
        *reinterpret_cast<const float4*>(X + (size_t)t*D_DIM + off);
    }
    __syncthreads();
    for (int s = 0; s < 8; ++s){
      const int e = wv*8 + s;
      const float* wr = WG + (size_t)e*D_DIM;
      double accd = 0.0;
      #pragma unroll
      for (int it = 0; it < 8; ++it){
        float4 w4 = *reinterpret_cast<const float4*>(wr + it*256 + lane*4);
        float4 x4 = *reinterpret_cast<const float4*>(xl + it*256 + lane*4);
        accd += (double)x4.x * (double)w4.x;
        accd += (double)x4.y * (double)w4.y;
        accd += (double)x4.z * (double)w4.z;
        accd += (double)x4.w * (double)w4.w;
      }
      #pragma unroll
      for (int off = 1; off < 64; off <<= 1) accd += __shfl_xor(accd, off, 64);
      if (lane == 0)
        lz[e] = accd + (double)NZ[(size_t)t*E_EXP + e] * (double)NW[e];
    }
    __syncthreads();
    if (tid == 0){
      double b1 = -1e300, b2 = -1e300; int j1 = 0, j2 = 0;
      for (int q = 0; q < 64; ++q){
        double v = lz[q];
        if (v > b1){ b2 = b1; j2 = j1; b1 = v; j1 = q; }
        else if (v > b2){ b2 = v; j2 = q; }
      }
      double ee = exp(b2 - b1);
      sfg[0] = (float)(1.0 / (1.0 + ee));
      sfg[1] = (float)(ee / (1.0 + ee));
      sfi[0] = j1; sfi[1] = j2;
      OUT[(size_t)T_TOK*E_EXP + (size_t)t*2]     = (float)j1;
      OUT[(size_t)T_TOK*E_EXP + (size_t)t*2 + 1] = (float)j2;
    }
    __syncthreads();
    if (tid < 64)
      OUT[(size_t)t*E_EXP + tid] = (tid == sfi[0]) ? sfg[0] :
                                   ((tid == sfi[1]) ? sfg[1] : 0.0f);
    __syncthreads();
  }

  // ---- last-block-done loss ----
  if (tid == 0){
    __threadfence();
    *stk = atomicAdd(DONE, 1);
  }
  __syncthreads();
  if (*stk == (int)gridDim.x - 1){
    if (tid < 64){
      double v = atomicAdd(&ESUM[tid], 0.0);   // coherent RMW read
      double d = v * (1.0 / T_TOK) - (1.0 / 64.0);
      double sq = d * d;
      #pragma unroll
      for (int off = 1; off < 64; off <<= 1) sq += __shfl_xor(sq, off, 64);
      if (tid == 0) OUT[(size_t)T_TOK*E_EXP + T_TOK*2] = (float)(sq * (0.01 / 64.0));
    }
  }
}

extern "C" void kernel_launch(void* const* d_in, const int* in_sizes, int n_in,
                              void* d_out, int out_size, void* d_ws, size_t ws_size,
                              hipStream_t stream)
{
  const float* X  = (const float*)d_in[0];
  const float* NZ = (const float*)d_in[1];
  const float* WG = (const float*)d_in[2];
  const float* NW = (const float*)d_in[3];
  float* OUT = (float*)d_out;
  char*  ws  = (char*)d_ws;
  ushort_t* WHI = (ushort_t*)(ws + WS_WHI);
  ushort_t* WLO = (ushort_t*)(ws + WS_WLO);
  double* ESUM = (double*)(ws + WS_SUM);
  int*   DONE  = (int*)(ws + WS_DONE);

  wsplit_kernel<<<dim3(64), dim3(256), 0, stream>>>(WG, WHI, WLO, ESUM, DONE);
  moe_main<<<dim3(T_TOK/32), dim3(512), 0, stream>>>(X, NZ, WHI, WLO, NW, WG,
                                                     OUT, ESUM, DONE);
}

// Round 16
// 111.964 us; speedup vs baseline: 2.9515x; 1.3776x over previous
//
#include <hip/hip_runtime.h>
#include <hip/hip_bf16.h>

#define T_TOK 16384
#define D_DIM 2048
#define E_EXP 64
#define TAU   2e-3f

typedef __bf16 bf16x8 __attribute__((ext_vector_type(8)));
typedef float  f32x16 __attribute__((ext_vector_type(16)));
typedef unsigned short ushort_t;

// workspace layout (bytes)
#define WS_WHI  0                    // ushort[16 chunks][1024 granule-slots][8] = 256KB
#define WS_WLO  (256*1024)
#define WS_SUM  (512*1024)           // double[64] expert prob sums
#define WS_CNT  (512*1024 + 512)     // int flag count
#define WS_FLG  (512*1024 + 1024)    // int[T] flagged rows

__device__ __forceinline__ unsigned short bf16_rne(float x){
  unsigned int u = __float_as_uint(x);
  return (unsigned short)((u + 0x7FFFu + ((u >> 16) & 1u)) >> 16);
}

__device__ __forceinline__ void ins3(float& v1, int& i1, float& v2, int& i2,
                                     float& v3, int& i3, float v, int i){
  if (v > v1 || (v == v1 && i < i1)) { v3=v2; i3=i2; v2=v1; i2=i1; v1=v; i1=i; }
  else if (v > v2 || (v == v2 && i < i2)) { v3=v2; i3=i2; v2=v; i2=i; }
  else if (v > v3 || (v == v3 && i < i3)) { v3=v; i3=i; }
}

__device__ __forceinline__ void gload16(const void* g, const void* l){
  __builtin_amdgcn_global_load_lds(
      (const __attribute__((address_space(1))) unsigned int*)g,
      (__attribute__((address_space(3))) unsigned int*)l, 16, 0, 0);
}

// Fragment-pack W hi/lo bf16 (layout R10's main reads) — COALESCED reads:
// block b = W row e (contiguous 8KB); scattered 16B writes absorbed by L2.
// Granule G = c*1024 + w*128 + eh*64 + kg*32 + m holds
// W[eh*32+m][c*128 + w*16 + kg*8 + j]  (verified compatible: passed in R15).
__global__ void wsplit_kernel(const float* __restrict__ W,
                              ushort_t* __restrict__ whi, ushort_t* __restrict__ wlo,
                              double* __restrict__ ESUM, int* __restrict__ FCNT){
  const int t = threadIdx.x;               // 64 blocks x 256 thr
  const int e = blockIdx.x;
  if (e == 0){
    if (t < 64) ESUM[t] = 0.0;
    else if (t == 64) *FCNT = 0;
  }
  const int k0 = t * 8;
  const float* src = W + (size_t)e*D_DIM + k0;
  float4 w0 = *reinterpret_cast<const float4*>(src);
  float4 w1 = *reinterpret_cast<const float4*>(src + 4);
  float f[8] = {w0.x,w0.y,w0.z,w0.w,w1.x,w1.y,w1.z,w1.w};
  unsigned h[8], lo[8];
  #pragma unroll
  for (int i = 0; i < 8; ++i){
    h[i]  = bf16_rne(f[i]);
    lo[i] = bf16_rne(f[i] - __uint_as_float(h[i] << 16));
  }
  uint4 hv = { h[0]|(h[1]<<16),  h[2]|(h[3]<<16),  h[4]|(h[5]<<16),  h[6]|(h[7]<<16) };
  uint4 lv = { lo[0]|(lo[1]<<16), lo[2]|(lo[3]<<16), lo[4]|(lo[5]<<16), lo[6]|(lo[7]<<16) };
  const int eh = e >> 5, m = e & 31;
  const int c  = k0 >> 7;
  const int w  = (k0 >> 4) & 7;
  const int kg = (k0 >> 3) & 1;
  const int G  = c*1024 + w*128 + eh*64 + kg*32 + m;
  *reinterpret_cast<uint4*>(whi + (size_t)G*8) = hv;
  *reinterpret_cast<uint4*>(wlo + (size_t)G*8) = lv;
}

// Main fused kernel — R10 mainloop VERBATIM (74.4us empirical best across 8
// structurally distinct designs; clock-corrected analysis shows ~48K cycles
// at the DVFS floor, not a counter-visible pipe limit).
__launch_bounds__(512, 4)
__global__ void moe_main(const float* __restrict__ X, const float* __restrict__ NZ,
                         const ushort_t* __restrict__ WHI, const ushort_t* __restrict__ WLO,
                         const float* __restrict__ NW, float* __restrict__ OUT,
                         double* __restrict__ ESUM, int* __restrict__ FCNT,
                         int* __restrict__ FLIST)
{
  __shared__ __align__(16) char smem[32768];

  const int tid  = threadIdx.x;
  const int lane = tid & 63;
  const int wv   = tid >> 6;   // 0..7
  const int eh   = wv & 1;     // expert half
  const int ks   = wv >> 1;    // K quarter of each chunk
  const int r0   = blockIdx.x << 5;
  const int m    = lane & 31;
  const int kg   = lane >> 5;

  // --- X staging addresses (per-lane source, wave-uniform LDS dst) ---
  const int n0   = wv*64 + lane;
  const int row0 = n0 >> 5, g0 = n0 & 31;
  const int gs0  = (g0 & 24) | ((g0 ^ row0) & 7);
  const char* px0 = (const char*)X + ((size_t)(r0 + row0)*D_DIM + gs0*4) * 4;
  const char* px1 = px0 + (size_t)16*D_DIM*4;
  const char* ldsx0 = smem +        wv*1024;
  const char* ldsx1 = smem + 8192 + wv*1024;

  const char* pwh = (const char*)WHI + (size_t)(ks*256 + eh*64 + lane)*16;
  const char* pwl = (const char*)WLO + (size_t)(ks*256 + eh*64 + lane)*16;

  const int gf0 = ks*8 + kg*2;
  const int gf1 = gf0 + 4;
  const int offA0 = m*512 + (((gf0  ) & 24) | (((gf0  ) ^ m) & 7))*16;
  const int offB0 = m*512 + (((gf0+1) & 24) | (((gf0+1) ^ m) & 7))*16;
  const int offA1 = m*512 + (((gf1  ) & 24) | (((gf1  ) ^ m) & 7))*16;
  const int offB1 = m*512 + (((gf1+1) & 24) | (((gf1+1) ^ m) & 7))*16;

  f32x16 acc;
  #pragma unroll
  for (int i = 0; i < 16; ++i) acc[i] = 0.0f;

  uint4 whA0, wlA0, whA1, wlA1;
  uint4 whB0, wlB0, whB1, wlB1;

  #define LOADW(c, H0, L0, H1, L1) do{                                         \
    H0 = *reinterpret_cast<const uint4*>(pwh + (size_t)(c)*16384);             \
    L0 = *reinterpret_cast<const uint4*>(pwl + (size_t)(c)*16384);             \
    H1 = *reinterpret_cast<const uint4*>(pwh + (size_t)(c)*16384 + 2048);      \
    L1 = *reinterpret_cast<const uint4*>(pwl + (size_t)(c)*16384 + 2048);      \
  }while(0)

  #define ISSUE(c, BUF, H0, L0, H1, L1) do{                                    \
    __builtin_amdgcn_sched_barrier(0);                                         \
    gload16(px0 + (size_t)(c)*512, ldsx0 + (BUF));                             \
    gload16(px1 + (size_t)(c)*512, ldsx1 + (BUF));                             \
    LOADW(c, H0, L0, H1, L1);                                                  \
    __builtin_amdgcn_sched_barrier(0);                                         \
  }while(0)

  #define CVT8(fa, fb, ah, al) do{                                             \
    float fv[8] = {fa.x,fa.y,fa.z,fa.w,fb.x,fb.y,fb.z,fb.w};                   \
    _Pragma("unroll")                                                          \
    for (int ii = 0; ii < 8; ++ii){                                            \
      __bf16 hh = (__bf16)fv[ii];                                              \
      ah[ii] = hh; al[ii] = (__bf16)(fv[ii] - (float)hh);                      \
    }                                                                          \
  }while(0)

  #define KS2(BUF, OA, OB, WH, WL) do{                                         \
    float4 fa = *reinterpret_cast<const float4*>(smem + (BUF) + (OA));         \
    float4 fb = *reinterpret_cast<const float4*>(smem + (BUF) + (OB));         \
    bf16x8 ah, al;                                                             \
    CVT8(fa, fb, ah, al);                                                      \
    bf16x8 bh = __builtin_bit_cast(bf16x8, WH);                                \
    bf16x8 bl = __builtin_bit_cast(bf16x8, WL);                                \
    acc = __builtin_amdgcn_mfma_f32_32x32x16_bf16(ah, bh, acc, 0, 0, 0);       \
    acc = __builtin_amdgcn_mfma_f32_32x32x16_bf16(ah, bl, acc, 0, 0, 0);       \
    acc = __builtin_amdgcn_mfma_f32_32x32x16_bf16(al, bh, acc, 0, 0, 0);       \
  }while(0)

  #define PHASE(cc, H0, L0, H1, L1, BUF, WNTOK, DOISS) do{                     \
    asm volatile("s_waitcnt vmcnt(" WNTOK ")" ::: "memory");                   \
    __builtin_amdgcn_sched_barrier(0);                                         \
    __builtin_amdgcn_s_barrier();                                              \
    KS2(BUF, offA0, offB0, H0, L0);                                            \
    KS2(BUF, offA1, offB1, H1, L1);                                            \
    __builtin_amdgcn_s_barrier();                                              \
    if (DOISS) ISSUE((cc) + 2, BUF, H0, L0, H1, L1);                           \
  }while(0)

  ISSUE(0, 0,     whA0, wlA0, whA1, wlA1);
  ISSUE(1, 16384, whB0, wlB0, whB1, wlB1);

  #pragma unroll 1
  for (int g = 0; g < 7; ++g){
    PHASE(2*g,     whA0, wlA0, whA1, wlA1, 0,     "6", 1);
    PHASE(2*g + 1, whB0, wlB0, whB1, wlB1, 16384, "6", 1);
  }
  PHASE(14, whA0, wlA0, whA1, wlA1, 0,     "6", 0);
  PHASE(15, whB0, wlB0, whB1, wlB1, 16384, "0", 0);

  #undef PHASE
  #undef KS2
  #undef CVT8
  #undef ISSUE
  #undef LOADW

  // ---- epilogue: K-quarter reduction (deterministic 4-phase chain) ----
  float* lgts = (float*)(smem);            // [32][64]
  float* nzs  = (float*)(smem + 8192);     // [32][64]
  float* prb  = (float*)(smem + 16384);    // [32][64]
  float* nws  = (float*)(smem + 24576);    // [64]
  const int ex = eh*32 + m;

  __syncthreads();
  if (ks == 0){
    #pragma unroll
    for (int r = 0; r < 16; ++r){
      int rr = (r & 3) + ((r >> 2) << 3) + (kg << 2);   // verified 32x32 C/D layout
      lgts[rr*64 + ex] = acc[r];
    }
  }
  __syncthreads();
  #pragma unroll
  for (int p = 1; p < 4; ++p){
    if (ks == p){
      #pragma unroll
      for (int r = 0; r < 16; ++r){
        int rr = (r & 3) + ((r >> 2) << 3) + (kg << 2);
        lgts[rr*64 + ex] += acc[r];
      }
    }
    __syncthreads();
  }

  // stage noise + noise_weight
  const int sr = tid >> 4, sc = tid & 15;
  *reinterpret_cast<float4*>(&nzs[sr*64 + sc*4]) =
    *reinterpret_cast<const float4*>(NZ + (size_t)(r0 + sr)*E_EXP + sc*4);
  if (tid < 64) nws[tid] = NW[tid];
  __syncthreads();

  // gating: waves 0..3, 8 lanes per row, 8 experts per lane
  if (wv < 4){
    const int rrow = (wv << 3) + (lane >> 3);
    const int j    = lane & 7;
    const int trow = r0 + rrow;
    float cl[8];
    float v1 = -INFINITY, v2 = -INFINITY, v3 = -INFINITY;
    int   i1 = 1 << 29,   i2 = 1 << 29,   i3 = 1 << 29;
    #pragma unroll
    for (int mm = 0; mm < 8; ++mm){
      int q = j + (mm << 3);
      float lg = lgts[rrow*64 + q];
      cl[mm] = lg;
      float vn = fmaf(nzs[rrow*64 + q], nws[q], lg);   // NOISY_STD = 1
      ins3(v1,i1,v2,i2,v3,i3, vn, q);
    }
    #pragma unroll
    for (int d = 1; d < 8; d <<= 1){
      float ov1 = __shfl_xor(v1, d, 8), ov2 = __shfl_xor(v2, d, 8), ov3 = __shfl_xor(v3, d, 8);
      int   oi1 = __shfl_xor(i1, d, 8), oi2 = __shfl_xor(i2, d, 8), oi3 = __shfl_xor(i3, d, 8);
      ins3(v1,i1,v2,i2,v3,i3, ov1, oi1);
      ins3(v1,i1,v2,i2,v3,i3, ov2, oi2);
      ins3(v1,i1,v2,i2,v3,i3, ov3, oi3);
    }
    float e1 = expf(v2 - v1);
    float g0g = 1.0f / (1.0f + e1);
    float g1g = e1 * g0g;

    float mx = cl[0];
    #pragma unroll
    for (int mm = 1; mm < 8; ++mm) mx = fmaxf(mx, cl[mm]);
    #pragma unroll
    for (int d = 1; d < 8; d <<= 1) mx = fmaxf(mx, __shfl_xor(mx, d, 8));
    float sum = 0.0f, exv[8];
    #pragma unroll
    for (int mm = 0; mm < 8; ++mm){ exv[mm] = expf(cl[mm] - mx); sum += exv[mm]; }
    #pragma unroll
    for (int d = 1; d < 8; d <<= 1) sum += __shfl_xor(sum, d, 8);
    float inv = 1.0f / sum;
    #pragma unroll
    for (int mm = 0; mm < 8; ++mm) prb[rrow*64 + j + (mm << 3)] = exv[mm] * inv;

    if (j == 0){
      OUT[(size_t)T_TOK*E_EXP + (size_t)trow*2]     = (float)i1;
      OUT[(size_t)T_TOK*E_EXP + (size_t)trow*2 + 1] = (float)i2;
      if ((v1 - v2 < TAU) || (v2 - v3 < TAU)){   // near-tie -> fp64 fixup
        int slot = atomicAdd(FCNT, 1);
        FLIST[slot] = trow;
      }
    }
    #pragma unroll
    for (int mm = 0; mm < 8; ++mm){
      int q = j + (mm << 3);
      lgts[rrow*64 + q] = (q == i1) ? g0g : ((q == i2) ? g1g : 0.0f);
    }
  }
  __syncthreads();

  // coalesced gates write (512 threads x float4)
  *reinterpret_cast<float4*>(OUT + (size_t)(r0 + sr)*E_EXP + sc*4) =
    *reinterpret_cast<const float4*>(&lgts[sr*64 + sc*4]);
  // per-expert prob column sums -> one f64 atomic per expert per block
  if (tid < 64){
    float s0 = 0.0f;
    #pragma unroll 8
    for (int rr2 = 0; rr2 < 32; ++rr2) s0 += prb[rr2*64 + tid];
    atomicAdd(&ESUM[tid], (double)s0);
  }
}

// Merged finalize: block 0 = load-balance loss (parallel ESUM reads);
// blocks 1..256 grid-stride the COMPACT near-tie list (fp64 recompute).
__launch_bounds__(256)
__global__ void moe_finalize(const float* __restrict__ X, const float* __restrict__ NZ,
                             const float* __restrict__ WG, const float* __restrict__ NW,
                             float* __restrict__ OUT, const double* __restrict__ ESUM,
                             const int* __restrict__ FCNT, const int* __restrict__ FLIST)
{
  if (blockIdx.x == 0){
    if (threadIdx.x < 64){
      const int e = threadIdx.x;
      double d = ESUM[e] * (1.0 / T_TOK) - (1.0 / 64.0);
      double sq = d * d;
      #pragma unroll
      for (int off = 1; off < 64; off <<= 1) sq += __shfl_xor(sq, off, 64);
      if (e == 0) OUT[(size_t)T_TOK*E_EXP + T_TOK*2] = (float)(sq * (0.01 / 64.0));
    }
    return;
  }

  __shared__ __align__(16) float xl[2048];
  __shared__ double lz[64];
  __shared__ int   si1, si2;
  __shared__ float sg0, sg1;
  const int n    = *FCNT;
  const int lane = threadIdx.x & 63;
  const int wv   = threadIdx.x >> 6;
  for (int idx = blockIdx.x - 1; idx < n; idx += 256){
    const int t = FLIST[idx];
    {
      int off = threadIdx.x * 8;
      *reinterpret_cast<float4*>(xl + off) =
        *reinterpret_cast<const float4*>(X + (size_t)t*D_DIM + off);
      *reinterpret_cast<float4*>(xl + off + 4) =
        *reinterpret_cast<const float4*>(X + (size_t)t*D_DIM + off + 4);
    }
    __syncthreads();
    for (int s = 0; s < 16; ++s){
      const int e = wv*16 + s;
      const float* wr = WG + (size_t)e*D_DIM;
      double acc = 0.0;
      #pragma unroll
      for (int it = 0; it < 8; ++it){
        float4 w4 = *reinterpret_cast<const float4*>(wr + it*256 + lane*4);
        float4 x4 = *reinterpret_cast<const float4*>(xl + it*256 + lane*4);
        acc += (double)x4.x * (double)w4.x;
        acc += (double)x4.y * (double)w4.y;
        acc += (double)x4.z * (double)w4.z;
        acc += (double)x4.w * (double)w4.w;
      }
      #pragma unroll
      for (int off = 1; off < 64; off <<= 1) acc += __shfl_xor(acc, off, 64);
      if (lane == 0)
        lz[e] = acc + (double)NZ[(size_t)t*E_EXP + e] * (double)NW[e];
    }
    __syncthreads();
    if (threadIdx.x == 0){
      double b1 = -1e300, b2 = -1e300; int j1 = 0, j2 = 0;
      for (int q = 0; q < 64; ++q){
        double v = lz[q];
        if (v > b1){ b2 = b1; j2 = j1; b1 = v; j1 = q; }
        else if (v > b2){ b2 = v; j2 = q; }
      }
      double ee = exp(b2 - b1);
      sg0 = (float)(1.0 / (1.0 + ee));
      sg1 = (float)(ee / (1.0 + ee));
      si1 = j1; si2 = j2;
      OUT[(size_t)T_TOK*E_EXP + (size_t)t*2]     = (float)j1;
      OUT[(size_t)T_TOK*E_EXP + (size_t)t*2 + 1] = (float)j2;
    }
    __syncthreads();
    if (threadIdx.x < 64)
      OUT[(size_t)t*E_EXP + threadIdx.x] = (threadIdx.x == si1) ? sg0 :
                                           ((threadIdx.x == si2) ? sg1 : 0.0f);
    __syncthreads();
  }
}

extern "C" void kernel_launch(void* const* d_in, const int* in_sizes, int n_in,
                              void* d_out, int out_size, void* d_ws, size_t ws_size,
                              hipStream_t stream)
{
  const float* X  = (const float*)d_in[0];
  const float* NZ = (const float*)d_in[1];
  const float* WG = (const float*)d_in[2];
  const float* NW = (const float*)d_in[3];
  float* OUT = (float*)d_out;
  char*  ws  = (char*)d_ws;
  ushort_t* WHI = (ushort_t*)(ws + WS_WHI);
  ushort_t* WLO = (ushort_t*)(ws + WS_WLO);
  double* ESUM = (double*)(ws + WS_SUM);
  int* FCNT  = (int*)(ws + WS_CNT);
  int* FLIST = (int*)(ws + WS_FLG);

  wsplit_kernel<<<dim3(64), dim3(256), 0, stream>>>(WG, WHI, WLO, ESUM, FCNT);
  moe_main<<<dim3(T_TOK/32), dim3(512), 0, stream>>>(X, NZ, WHI, WLO, NW, OUT, ESUM, FCNT, FLIST);
  moe_finalize<<<dim3(257), dim3(256), 0, stream>>>(X, NZ, WG, NW, OUT, ESUM, FCNT, FLIST);
}